// Round 8
// baseline (122.911 us; speedup 1.0000x reference)
//
#include <hip/hip_runtime.h>
#include <stdint.h>
#include <stddef.h>

#define NB 4
#define NL 2048
#define MODEL 512
#define NH 8
#define HD 64

// Q pre-scale: (1/sqrt(64)) * log2(e) -> scores in log2 domain
#define QSCALE 0.18033688011112042f

typedef __attribute__((ext_vector_type(8))) short short8;
typedef __attribute__((ext_vector_type(8))) __bf16 bf16x8;
typedef __attribute__((ext_vector_type(4))) float f32x4;
typedef __attribute__((ext_vector_type(16))) float f32x16;
typedef __attribute__((ext_vector_type(2))) unsigned int u32x2;

// round-to-nearest-even fp32 -> bf16 (bit pattern)
static __device__ __forceinline__ unsigned short f2bf(float x) {
  union { float f; unsigned u; } v; v.f = x;
  unsigned r = v.u + 0x7FFFu + ((v.u >> 16) & 1u);
  return (unsigned short)(r >> 16);
}

// packed fp32x2 -> bf16x2 (single HW instruction)
static __device__ __forceinline__ unsigned cvtpk(float lo, float hi) {
  unsigned r;
  asm("v_cvt_pk_bf16_f32 %0, %1, %2" : "=v"(r) : "v"(lo), "v"(hi));
  return r;
}

static __device__ __forceinline__ f32x4 mfma16(short8 a, short8 b, f32x4 c) {
  return __builtin_amdgcn_mfma_f32_16x16x32_bf16(
      __builtin_bit_cast(bf16x8, a), __builtin_bit_cast(bf16x8, b), c, 0, 0, 0);
}

static __device__ __forceinline__ f32x16 mfma32(short8 a, short8 b, f32x16 c) {
  return __builtin_amdgcn_mfma_f32_32x32x16_bf16(
      __builtin_bit_cast(bf16x8, a), __builtin_bit_cast(bf16x8, b), c, 0, 0, 0);
}

#define GLOAD_LDS(gp, lp)                                                      \
  __builtin_amdgcn_global_load_lds(                                            \
      (const __attribute__((address_space(1))) void*)(gp),                     \
      (__attribute__((address_space(3))) void*)(lp), 16, 0, 0)

// ---------------------------------------------------------------------------
// Merged Q/K/V projection: grid 768 = 3 x 256, 256 thr (4 waves 2x2).
// C[m][n] = A[m][k] * W[n][k]; which 0: Q bf16 (scaled), 1: K bf16,
// 2: V transposed Vt[b][n][s].
// ---------------------------------------------------------------------------
__global__ __launch_bounds__(256) void qkv512(const float* __restrict__ Aq,
                                              const float* __restrict__ Ak,
                                              const float* __restrict__ Av,
                                              const float* __restrict__ Wqp,
                                              const float* __restrict__ Wkp,
                                              const float* __restrict__ Wvp,
                                              unsigned short* __restrict__ Qo,
                                              unsigned short* __restrict__ Ko,
                                              unsigned short* __restrict__ Vto) {
  __shared__ unsigned short Alds[128][72];
  __shared__ unsigned short Wlds[128][72];

  const int which = blockIdx.x >> 8;
  const int bid = blockIdx.x & 255;
  const float* A = which == 0 ? Aq : which == 1 ? Ak : Av;
  const float* W = which == 0 ? Wqp : which == 1 ? Wkp : Wvp;

  const int tid = threadIdx.x;
  const int bn = bid & 3;
  const int bm = bid >> 2;
  const int mbase = bm * 128, nbase = bn * 128;
  const int wid = tid >> 6, lane = tid & 63;
  const int lo = lane & 15, grp = lane >> 4;
  const int wm = wid >> 1, wn = wid & 1;

  f32x4 acc[4][4] = {};

#pragma unroll 1
  for (int kb = 0; kb < 8; ++kb) {
#pragma unroll
    for (int it = 0; it < 8; ++it) {
      int id = tid + it * 256;
      int row = id >> 4, cg = id & 15;
      float4 v = *(const float4*)(A + (size_t)(mbase + row) * 512 + kb * 64 + cg * 4);
      uint2 w; w.x = cvtpk(v.x, v.y); w.y = cvtpk(v.z, v.w);
      *(uint2*)&Alds[row][cg * 4] = w;
    }
#pragma unroll
    for (int it = 0; it < 8; ++it) {
      int id = tid + it * 256;
      int row = id >> 4, cg = id & 15;
      float4 v = *(const float4*)(W + (size_t)(nbase + row) * 512 + kb * 64 + cg * 4);
      uint2 w; w.x = cvtpk(v.x, v.y); w.y = cvtpk(v.z, v.w);
      *(uint2*)&Wlds[row][cg * 4] = w;
    }
    __syncthreads();

#pragma unroll
    for (int kk = 0; kk < 2; ++kk) {
      short8 aw[4], ba[4];
#pragma unroll
      for (int f = 0; f < 4; ++f)
        aw[f] = *(const short8*)&Wlds[wn * 64 + f * 16 + lo][kk * 32 + grp * 8];
#pragma unroll
      for (int f = 0; f < 4; ++f)
        ba[f] = *(const short8*)&Alds[wm * 64 + f * 16 + lo][kk * 32 + grp * 8];
#pragma unroll
      for (int mf = 0; mf < 4; ++mf)
#pragma unroll
        for (int nf = 0; nf < 4; ++nf)
          acc[mf][nf] = mfma16(aw[nf], ba[mf], acc[mf][nf]);
    }
    __syncthreads();
  }

  const float scale = (which == 0) ? QSCALE : 1.0f;
#pragma unroll
  for (int mf = 0; mf < 4; ++mf)
#pragma unroll
    for (int nf = 0; nf < 4; ++nf) {
      int m = mbase + wm * 64 + mf * 16 + lo;
      int n0 = nbase + wn * 64 + nf * 16 + grp * 4;
      f32x4 a = acc[mf][nf];
      if (which < 2) {
        unsigned short* C = which == 0 ? Qo : Ko;
        uint2 w;
        w.x = cvtpk(a[0] * scale, a[1] * scale);
        w.y = cvtpk(a[2] * scale, a[3] * scale);
        *(uint2*)(C + (size_t)m * 512 + n0) = w;
      } else {
        int b = m >> 11, s = m & 2047;
#pragma unroll
        for (int i = 0; i < 4; ++i)
          Vto[((size_t)b * 512 + n0 + i) * 2048 + s] = f2bf(a[i]);
      }
    }
}

// ---------------------------------------------------------------------------
// Output projection (bf16 A, fp32 out). 128x128 tiles, grid 256.
// ---------------------------------------------------------------------------
__global__ __launch_bounds__(256) void gemmWo(const unsigned short* __restrict__ A,
                                              const float* __restrict__ W,
                                              float* __restrict__ C) {
  __shared__ unsigned short Alds[128][72];
  __shared__ unsigned short Wlds[128][72];

  const int tid = threadIdx.x;
  const int bn = blockIdx.x & 3;
  const int bm = blockIdx.x >> 2;
  const int mbase = bm * 128, nbase = bn * 128;
  const int wid = tid >> 6, lane = tid & 63;
  const int lo = lane & 15, grp = lane >> 4;
  const int wm = wid >> 1, wn = wid & 1;

  f32x4 acc[4][4] = {};

#pragma unroll 1
  for (int kb = 0; kb < 8; ++kb) {
#pragma unroll
    for (int it = 0; it < 4; ++it) {
      int id = tid + it * 256;
      int row = id >> 3, cg = id & 7;
      uint4 v = *(const uint4*)(A + (size_t)(mbase + row) * 512 + kb * 64 + cg * 8);
      *(uint4*)&Alds[row][cg * 8] = v;
    }
#pragma unroll
    for (int it = 0; it < 8; ++it) {
      int id = tid + it * 256;
      int row = id >> 4, cg = id & 15;
      float4 v = *(const float4*)(W + (size_t)(nbase + row) * 512 + kb * 64 + cg * 4);
      uint2 w; w.x = cvtpk(v.x, v.y); w.y = cvtpk(v.z, v.w);
      *(uint2*)&Wlds[row][cg * 4] = w;
    }
    __syncthreads();

#pragma unroll
    for (int kk = 0; kk < 2; ++kk) {
      short8 aw[4], ba[4];
#pragma unroll
      for (int f = 0; f < 4; ++f)
        aw[f] = *(const short8*)&Wlds[wn * 64 + f * 16 + lo][kk * 32 + grp * 8];
#pragma unroll
      for (int f = 0; f < 4; ++f)
        ba[f] = *(const short8*)&Alds[wm * 64 + f * 16 + lo][kk * 32 + grp * 8];
#pragma unroll
      for (int mf = 0; mf < 4; ++mf)
#pragma unroll
        for (int nf = 0; nf < 4; ++nf)
          acc[mf][nf] = mfma16(aw[nf], ba[mf], acc[mf][nf]);
    }
    __syncthreads();
  }

#pragma unroll
  for (int mf = 0; mf < 4; ++mf)
#pragma unroll
    for (int nf = 0; nf < 4; ++nf) {
      int m = mbase + wm * 64 + mf * 16 + lo;
      int n0 = nbase + wn * 64 + nf * 16 + grp * 4;
      f32x4 a = acc[mf][nf];
      float4 o;
      o.x = a[0]; o.y = a[1]; o.z = a[2]; o.w = a[3];
      *(float4*)(C + (size_t)m * 512 + n0) = o;
    }
}

// ---------------------------------------------------------------------------
// Flash attention v8: grid 1024 (32 bh x 32 qb of 64 q), 512 thr = 8 waves =
// 2 qh (32 q each) x 4 s-quarters (512 s each, 16 tiles of KVBLK=32).
// 2 blocks/CU -> 16 waves/CU, 4/SIMD (the r7 stall fix).
// Unnormalized softmax (P = exp2(s), shift-invariant out), in-register P via
// cvt_pk + permlane32_swap, K+V LDS via global_load_lds DMA:
//   K quarter [32 s][128B rows], slot ^= row&7 (class-optimal)
//   V quarter [64 d][64B rows],  slot ^= (row>>1)&3 (class-optimal)
// Each wave DMAs exactly one K- or V-quarter (4 instrs/tile). S-quarter
// partials combined in-LDS (2 pairwise rounds over dead K/V buffers).
// ---------------------------------------------------------------------------
__global__ __launch_bounds__(512, 4) void attn64q(const unsigned short* __restrict__ Qg,
                                                  const unsigned short* __restrict__ Kg,
                                                  const unsigned short* __restrict__ Vt,
                                                  unsigned short* __restrict__ Og) {
  __shared__ __align__(16) char LDS[65536];
  // K region: sh*8192 + buf*4096   (4 quarters x dbuf x 4 KB)
  // V region: 32768 + sh*8192 + buf*4096

  const int tid = threadIdx.x;
  const int wid = tid >> 6, lane = tid & 63;
  const int ln31 = lane & 31, hl = lane >> 5;
  const int qh = wid & 1, sh = wid >> 1;          // sh = s-quarter 0..3

  // XCD chunk swizzle (1024 blocks, 128/XCD = 4 bh groups)
  const int lb = ((blockIdx.x & 7) << 7) | (blockIdx.x >> 3);
  const int bh = lb >> 5, qb = lb & 31;
  const int b = bh >> 3, h = bh & 7;

  const unsigned short* Kbh = Kg + (size_t)b * 2048 * 512 + h * 64;
  const unsigned short* Vbh = Vt + ((size_t)b * 512 + h * 64) * 2048;
  const int q0 = qb * 64 + qh * 32 + ln31;        // this lane's q-column

  // Q B-fragments: col=q, k(d) = ks*16 + hl*8 + j
  short8 qf[4];
#pragma unroll
  for (int ks = 0; ks < 4; ++ks)
    qf[ks] = *(const short8*)(Qg + ((size_t)b * 2048 + q0) * 512 + h * 64 + ks * 16 + hl * 8);

  // ---- DMA staging: wave wid<4 stages K quarter wid; wid>=4 V quarter wid-4
  const unsigned short* kg = Kbh + (size_t)(wid * 512 + (lane >> 3)) * 512 +
                             ((lane & 7) ^ (lane >> 3)) * 8;          // wid<4
  const unsigned short* vg = Vbh + (size_t)(lane >> 2) * 2048 + (wid - 4) * 512 +
                             (((lane & 3) ^ ((lane >> 3) & 3))) * 8;  // wid>=4
  char* kdst = LDS + wid * 8192;                  // + buf*4096 + g*1024
  char* vdst = LDS + 32768 + (wid - 4) * 8192;

  // ---- read addressing (precomputed, tile-invariant) ----
  char* kbase = LDS + sh * 8192 + ln31 * 128;     // + buf*4096 + okk[ks]
  const int swk = ln31 & 7;
  const int ok0 = ((0 + hl) ^ swk) * 16;
  const int ok1 = ((2 + hl) ^ swk) * 16;
  const int ok2 = ((4 + hl) ^ swk) * 16;
  const int ok3 = ((6 + hl) ^ swk) * 16;
  char* vbase = LDS + 32768 + sh * 8192;          // + buf*4096 + row*64 + ovv
  const int swv = (ln31 >> 1) & 3;
  const int ov0 = ((0 + hl) ^ swv) * 16;
  const int ov1 = ((2 + hl) ^ swv) * 16;
  const int vb0 = ln31 * 64, vb1 = (32 + ln31) * 64;

  f32x16 o0 = {}, o1 = {};
  float lsum = 0.f;

  // prologue: stage tile 0 into buf 0
  if (wid < 4) {
#pragma unroll
    for (int g = 0; g < 4; ++g)
      GLOAD_LDS(kg + (size_t)g * 8 * 512, kdst + g * 1024);
  } else {
#pragma unroll
    for (int g = 0; g < 4; ++g)
      GLOAD_LDS(vg + (size_t)g * 16 * 2048, vdst + g * 1024);
  }
  __syncthreads();

  int cur = 0;
#pragma unroll 1
  for (int t = 0; t < 16; ++t) {
    // prefetch next tile into back buffer
    if (t < 15) {
      if (wid < 4) {
        const unsigned short* kp = kg + (size_t)(t + 1) * 32 * 512;
        char* kd = kdst + (cur ^ 1) * 4096;
#pragma unroll
        for (int g = 0; g < 4; ++g)
          GLOAD_LDS(kp + (size_t)g * 8 * 512, kd + g * 1024);
      } else {
        const unsigned short* vp = vg + (t + 1) * 32;
        char* vd = vdst + (cur ^ 1) * 4096;
#pragma unroll
        for (int g = 0; g < 4; ++g)
          GLOAD_LDS(vp + (size_t)g * 16 * 2048, vd + g * 1024);
      }
    }

    const char* kr = kbase + cur * 4096;
    const char* vr = vbase + cur * 4096;

    // ---- QK^T: D[s(32)][q(32)] ----
    f32x16 s = {};
    __builtin_amdgcn_s_setprio(1);
    {
      short8 k0 = *(const short8*)(kr + ok0);
      short8 k1 = *(const short8*)(kr + ok1);
      short8 k2 = *(const short8*)(kr + ok2);
      short8 k3 = *(const short8*)(kr + ok3);
      s = mfma32(k0, qf[0], s);
      s = mfma32(k1, qf[1], s);
      s = mfma32(k2, qf[2], s);
      s = mfma32(k3, qf[3], s);
    }
    __builtin_amdgcn_s_setprio(0);

    // ---- unnormalized softmax: P = exp2(s) ----
    unsigned c[8];
    float psum = 0.f;
#pragma unroll
    for (int i = 0; i < 8; ++i) {
      float ea = __builtin_exp2f(s[2 * i]), eb = __builtin_exp2f(s[2 * i + 1]);
      psum += ea + eb;
      c[i] = cvtpk(ea, eb);
    }
    lsum += psum + __shfl_xor(psum, 32);

    // ---- redistribute P into PV B-fragments (permlane32_swap) ----
    {
      u32x2 r;
      r = __builtin_amdgcn_permlane32_swap(c[0], c[2], false, false); c[0] = r[0]; c[2] = r[1];
      r = __builtin_amdgcn_permlane32_swap(c[1], c[3], false, false); c[1] = r[0]; c[3] = r[1];
      r = __builtin_amdgcn_permlane32_swap(c[4], c[6], false, false); c[4] = r[0]; c[6] = r[1];
      r = __builtin_amdgcn_permlane32_swap(c[5], c[7], false, false); c[5] = r[0]; c[7] = r[1];
    }
    short8 pf0, pf1;
    {
      union { unsigned u[4]; short8 s8; } t2;
      t2.u[0] = c[0]; t2.u[1] = c[1]; t2.u[2] = c[2]; t2.u[3] = c[3]; pf0 = t2.s8;
      t2.u[0] = c[4]; t2.u[1] = c[5]; t2.u[2] = c[6]; t2.u[3] = c[7]; pf1 = t2.s8;
    }

    // ---- PV: O[d][q] += V[d][s] * P[s][q] ----
    __builtin_amdgcn_s_setprio(1);
    {
      short8 v00 = *(const short8*)(vr + vb0 + ov0);
      short8 v01 = *(const short8*)(vr + vb0 + ov1);
      short8 v10 = *(const short8*)(vr + vb1 + ov0);
      short8 v11 = *(const short8*)(vr + vb1 + ov1);
      o0 = mfma32(v00, pf0, o0);
      o0 = mfma32(v01, pf1, o0);
      o1 = mfma32(v10, pf0, o1);
      o1 = mfma32(v11, pf1, o1);
    }
    __builtin_amdgcn_s_setprio(0);

    __syncthreads();   // drains DMA prefetch + orders LDS buffer reuse
    cur ^= 1;
  }

  // ---- combine s-quarters: 2 pairwise rounds over dead K/V LDS ----
  // lane record: 36 floats (144 B): o0[16], o1[16], l, pad
  {
    float* wp = (float*)(LDS + (wid & 3) * 9216) + lane * 36;
    if (wid >= 4) {  // sh 2,3 write
      float4* w4 = (float4*)wp;
#pragma unroll
      for (int i = 0; i < 4; ++i) {
        w4[i]     = make_float4(o0[4 * i], o0[4 * i + 1], o0[4 * i + 2], o0[4 * i + 3]);
        w4[4 + i] = make_float4(o1[4 * i], o1[4 * i + 1], o1[4 * i + 2], o1[4 * i + 3]);
      }
      wp[32] = lsum;
    }
    __syncthreads();
    if (wid < 4) {   // sh 0,1 absorb sh 2,3
      const float* rp = (const float*)(LDS + wid * 9216) + lane * 36;
#pragma unroll
      for (int i = 0; i < 16; ++i) { o0[i] += rp[i]; o1[i] += rp[16 + i]; }
      lsum += rp[32];
    }
    __syncthreads();
    if (wid == 2 || wid == 3) {  // sh 1 writes
      float* wp2 = (float*)(LDS + (wid - 2) * 9216) + lane * 36;
      float4* w4 = (float4*)wp2;
#pragma unroll
      for (int i = 0; i < 4; ++i) {
        w4[i]     = make_float4(o0[4 * i], o0[4 * i + 1], o0[4 * i + 2], o0[4 * i + 3]);
        w4[4 + i] = make_float4(o1[4 * i], o1[4 * i + 1], o1[4 * i + 2], o1[4 * i + 3]);
      }
      wp2[32] = lsum;
    }
    __syncthreads();
    if (wid < 2) {   // sh 0 absorbs sh 1, finalize, store
      const float* rp = (const float*)(LDS + wid * 9216) + lane * 36;
#pragma unroll
      for (int i = 0; i < 16; ++i) { o0[i] += rp[i]; o1[i] += rp[16 + i]; }
      lsum += rp[32];

      float inv = 1.f / lsum;
#pragma unroll
      for (int dblk = 0; dblk < 2; ++dblk) {
        const f32x16& oo = dblk ? o1 : o0;
#pragma unroll
        for (int rg = 0; rg < 4; ++rg) {
          int d0 = dblk * 32 + rg * 8 + hl * 4;
          uint2 w;
          w.x = cvtpk(oo[rg * 4 + 0] * inv, oo[rg * 4 + 1] * inv);
          w.y = cvtpk(oo[rg * 4 + 2] * inv, oo[rg * 4 + 3] * inv);
          *(uint2*)(Og + ((size_t)b * 2048 + q0) * 512 + h * 64 + d0) = w;
        }
      }
    }
  }
}

// ---------------------------------------------------------------------------
extern "C" void kernel_launch(void* const* d_in, const int* in_sizes, int n_in,
                              void* d_out, int out_size, void* d_ws, size_t ws_size,
                              hipStream_t stream) {
  (void)in_sizes; (void)n_in; (void)out_size; (void)ws_size;
  const float* query = (const float*)d_in[0];
  const float* key   = (const float*)d_in[1];
  const float* value = (const float*)d_in[2];
  const float* Wq    = (const float*)d_in[3];
  const float* Wk    = (const float*)d_in[4];
  const float* Wv    = (const float*)d_in[5];
  const float* Wo    = (const float*)d_in[6];

  const size_t TOK = (size_t)NB * NL * MODEL;
  unsigned short* Qw = (unsigned short*)d_ws;
  unsigned short* Kw = Qw + TOK;
  unsigned short* Vw = Kw + TOK;   // transposed [b][h*64+d][s]
  unsigned short* Aw = Vw + TOK;   // attended [b][l][512]

  qkv512<<<768, 256, 0, stream>>>(query, key, value, Wq, Wk, Wv, Qw, Kw, Vw);
  attn64q<<<1024, 512, 0, stream>>>(Qw, Kw, Vw, Aw);
  gemmWo<<<256, 256, 0, stream>>>(Aw, Wo, (float*)d_out);
}

// Round 9
// 122.623 us; speedup vs baseline: 1.0023x; 1.0023x over previous
//
#include <hip/hip_runtime.h>
#include <stdint.h>
#include <stddef.h>

#define NB 4
#define NL 2048
#define MODEL 512
#define NH 8
#define HD 64

// Q pre-scale: (1/sqrt(64)) * log2(e) -> scores in log2 domain
#define QSCALE 0.18033688011112042f

typedef __attribute__((ext_vector_type(8))) short short8;
typedef __attribute__((ext_vector_type(8))) __bf16 bf16x8;
typedef __attribute__((ext_vector_type(4))) float f32x4;
typedef __attribute__((ext_vector_type(16))) float f32x16;
typedef __attribute__((ext_vector_type(2))) unsigned int u32x2;

// round-to-nearest-even fp32 -> bf16 (bit pattern)
static __device__ __forceinline__ unsigned short f2bf(float x) {
  union { float f; unsigned u; } v; v.f = x;
  unsigned r = v.u + 0x7FFFu + ((v.u >> 16) & 1u);
  return (unsigned short)(r >> 16);
}

// packed fp32x2 -> bf16x2 (single HW instruction)
static __device__ __forceinline__ unsigned cvtpk(float lo, float hi) {
  unsigned r;
  asm("v_cvt_pk_bf16_f32 %0, %1, %2" : "=v"(r) : "v"(lo), "v"(hi));
  return r;
}

static __device__ __forceinline__ f32x4 mfma16(short8 a, short8 b, f32x4 c) {
  return __builtin_amdgcn_mfma_f32_16x16x32_bf16(
      __builtin_bit_cast(bf16x8, a), __builtin_bit_cast(bf16x8, b), c, 0, 0, 0);
}

static __device__ __forceinline__ f32x16 mfma32(short8 a, short8 b, f32x16 c) {
  return __builtin_amdgcn_mfma_f32_32x32x16_bf16(
      __builtin_bit_cast(bf16x8, a), __builtin_bit_cast(bf16x8, b), c, 0, 0, 0);
}

#define GLOAD_LDS(gp, lp)                                                      \
  __builtin_amdgcn_global_load_lds(                                            \
      (const __attribute__((address_space(1))) void*)(gp),                     \
      (__attribute__((address_space(3))) void*)(lp), 16, 0, 0)

// ---------------------------------------------------------------------------
// Merged Q/K/V projection: grid 768 = 3 x 256, 256 thr (4 waves 2x2).
// ---------------------------------------------------------------------------
__global__ __launch_bounds__(256) void qkv512(const float* __restrict__ Aq,
                                              const float* __restrict__ Ak,
                                              const float* __restrict__ Av,
                                              const float* __restrict__ Wqp,
                                              const float* __restrict__ Wkp,
                                              const float* __restrict__ Wvp,
                                              unsigned short* __restrict__ Qo,
                                              unsigned short* __restrict__ Ko,
                                              unsigned short* __restrict__ Vto) {
  __shared__ unsigned short Alds[128][72];
  __shared__ unsigned short Wlds[128][72];

  const int which = blockIdx.x >> 8;
  const int bid = blockIdx.x & 255;
  const float* A = which == 0 ? Aq : which == 1 ? Ak : Av;
  const float* W = which == 0 ? Wqp : which == 1 ? Wkp : Wvp;

  const int tid = threadIdx.x;
  const int bn = bid & 3;
  const int bm = bid >> 2;
  const int mbase = bm * 128, nbase = bn * 128;
  const int wid = tid >> 6, lane = tid & 63;
  const int lo = lane & 15, grp = lane >> 4;
  const int wm = wid >> 1, wn = wid & 1;

  f32x4 acc[4][4] = {};

#pragma unroll 1
  for (int kb = 0; kb < 8; ++kb) {
#pragma unroll
    for (int it = 0; it < 8; ++it) {
      int id = tid + it * 256;
      int row = id >> 4, cg = id & 15;
      float4 v = *(const float4*)(A + (size_t)(mbase + row) * 512 + kb * 64 + cg * 4);
      uint2 w; w.x = cvtpk(v.x, v.y); w.y = cvtpk(v.z, v.w);
      *(uint2*)&Alds[row][cg * 4] = w;
    }
#pragma unroll
    for (int it = 0; it < 8; ++it) {
      int id = tid + it * 256;
      int row = id >> 4, cg = id & 15;
      float4 v = *(const float4*)(W + (size_t)(nbase + row) * 512 + kb * 64 + cg * 4);
      uint2 w; w.x = cvtpk(v.x, v.y); w.y = cvtpk(v.z, v.w);
      *(uint2*)&Wlds[row][cg * 4] = w;
    }
    __syncthreads();

#pragma unroll
    for (int kk = 0; kk < 2; ++kk) {
      short8 aw[4], ba[4];
#pragma unroll
      for (int f = 0; f < 4; ++f)
        aw[f] = *(const short8*)&Wlds[wn * 64 + f * 16 + lo][kk * 32 + grp * 8];
#pragma unroll
      for (int f = 0; f < 4; ++f)
        ba[f] = *(const short8*)&Alds[wm * 64 + f * 16 + lo][kk * 32 + grp * 8];
#pragma unroll
      for (int mf = 0; mf < 4; ++mf)
#pragma unroll
        for (int nf = 0; nf < 4; ++nf)
          acc[mf][nf] = mfma16(aw[nf], ba[mf], acc[mf][nf]);
    }
    __syncthreads();
  }

  const float scale = (which == 0) ? QSCALE : 1.0f;
#pragma unroll
  for (int mf = 0; mf < 4; ++mf)
#pragma unroll
    for (int nf = 0; nf < 4; ++nf) {
      int m = mbase + wm * 64 + mf * 16 + lo;
      int n0 = nbase + wn * 64 + nf * 16 + grp * 4;
      f32x4 a = acc[mf][nf];
      if (which < 2) {
        unsigned short* C = which == 0 ? Qo : Ko;
        uint2 w;
        w.x = cvtpk(a[0] * scale, a[1] * scale);
        w.y = cvtpk(a[2] * scale, a[3] * scale);
        *(uint2*)(C + (size_t)m * 512 + n0) = w;
      } else {
        int b = m >> 11, s = m & 2047;
#pragma unroll
        for (int i = 0; i < 4; ++i)
          Vto[((size_t)b * 512 + n0 + i) * 2048 + s] = f2bf(a[i]);
      }
    }
}

// ---------------------------------------------------------------------------
// Output projection (bf16 A, fp32 out). 128x128 tiles, grid 256.
// ---------------------------------------------------------------------------
__global__ __launch_bounds__(256) void gemmWo(const unsigned short* __restrict__ A,
                                              const float* __restrict__ W,
                                              float* __restrict__ C) {
  __shared__ unsigned short Alds[128][72];
  __shared__ unsigned short Wlds[128][72];

  const int tid = threadIdx.x;
  const int bn = blockIdx.x & 3;
  const int bm = blockIdx.x >> 2;
  const int mbase = bm * 128, nbase = bn * 128;
  const int wid = tid >> 6, lane = tid & 63;
  const int lo = lane & 15, grp = lane >> 4;
  const int wm = wid >> 1, wn = wid & 1;

  f32x4 acc[4][4] = {};

#pragma unroll 1
  for (int kb = 0; kb < 8; ++kb) {
#pragma unroll
    for (int it = 0; it < 4; ++it) {
      int id = tid + it * 256;
      int row = id >> 3, cg = id & 7;
      uint4 v = *(const uint4*)(A + (size_t)(mbase + row) * 512 + kb * 64 + cg * 8);
      *(uint4*)&Alds[row][cg * 8] = v;
    }
#pragma unroll
    for (int it = 0; it < 8; ++it) {
      int id = tid + it * 256;
      int row = id >> 4, cg = id & 15;
      float4 v = *(const float4*)(W + (size_t)(nbase + row) * 512 + kb * 64 + cg * 4);
      uint2 w; w.x = cvtpk(v.x, v.y); w.y = cvtpk(v.z, v.w);
      *(uint2*)&Wlds[row][cg * 4] = w;
    }
    __syncthreads();

#pragma unroll
    for (int kk = 0; kk < 2; ++kk) {
      short8 aw[4], ba[4];
#pragma unroll
      for (int f = 0; f < 4; ++f)
        aw[f] = *(const short8*)&Wlds[wn * 64 + f * 16 + lo][kk * 32 + grp * 8];
#pragma unroll
      for (int f = 0; f < 4; ++f)
        ba[f] = *(const short8*)&Alds[wm * 64 + f * 16 + lo][kk * 32 + grp * 8];
#pragma unroll
      for (int mf = 0; mf < 4; ++mf)
#pragma unroll
        for (int nf = 0; nf < 4; ++nf)
          acc[mf][nf] = mfma16(aw[nf], ba[mf], acc[mf][nf]);
    }
    __syncthreads();
  }

#pragma unroll
  for (int mf = 0; mf < 4; ++mf)
#pragma unroll
    for (int nf = 0; nf < 4; ++nf) {
      int m = mbase + wm * 64 + mf * 16 + lo;
      int n0 = nbase + wn * 64 + nf * 16 + grp * 4;
      f32x4 a = acc[mf][nf];
      float4 o;
      o.x = a[0]; o.y = a[1]; o.z = a[2]; o.w = a[3];
      *(float4*)(C + (size_t)m * 512 + n0) = o;
    }
}

// ---------------------------------------------------------------------------
// Flash attention v9: BARRIER-FREE main loop. Each wave owns a private 16 KB
// LDS region (K dbuf [2][32s][128B] + V dbuf [2][64d][64B]) staged via
// global_load_lds; sync is per-wave counted s_waitcnt vmcnt(8). Wave = 64 q
// (dual 32-q chains sharing K/V frags) x 1024 s (s-half). 32 t of KVBLK=32.
// Unnormalized softmax (P = exp2(s)); l via ones-MFMA; in-register P via
// cvt_pk + permlane32_swap. One barrier at end to combine s-halves.
// Grid 512 x 4 waves (2 blocks/CU, 8 independent waves/CU). XCD swizzle.
// ---------------------------------------------------------------------------
__global__ __launch_bounds__(256, 2) void attn_nb(const unsigned short* __restrict__ Qg,
                                                  const unsigned short* __restrict__ Kg,
                                                  const unsigned short* __restrict__ Vt,
                                                  unsigned short* __restrict__ Og) {
  __shared__ __align__(16) char LDS[65536];

  const int tid = threadIdx.x;
  const int wid = tid >> 6, lane = tid & 63;
  const int ln31 = lane & 31, hl = lane >> 5;
  const int qh = wid & 1, sh = wid >> 1;

  // XCD chunk swizzle (512 blocks, 64/XCD = 4 bh groups)
  const int lb = ((blockIdx.x & 7) << 6) | (blockIdx.x >> 3);
  const int bh = lb >> 4, qb = lb & 15;
  const int b = bh >> 3, h = bh & 7;

  const unsigned short* Kbh = Kg + (size_t)b * 2048 * 512 + h * 64;
  const unsigned short* Vbh = Vt + ((size_t)b * 512 + h * 64) * 2048;
  const int q0 = qb * 128 + qh * 64 + ln31;   // chain A; chain B = q0+32

  // Q B-fragments
  short8 qfA[4], qfB[4];
#pragma unroll
  for (int ks = 0; ks < 4; ++ks) {
    qfA[ks] = *(const short8*)(Qg + ((size_t)b * 2048 + q0) * 512 + h * 64 + ks * 16 + hl * 8);
    qfB[ks] = *(const short8*)(Qg + ((size_t)b * 2048 + q0 + 32) * 512 + h * 64 + ks * 16 + hl * 8);
  }

  // wave-private LDS: K [2][4096] at +0, V [2][4096] at +8192
  char* kbuf = LDS + wid * 16384;
  char* vbuf = kbuf + 8192;

  // staging geometry (pre-swizzled global source; LDS dest linear lane*16)
  const int krow = lane >> 3;                       // 0..7
  const int kslot = (lane & 7) ^ krow;              // K: slot ^= row&7
  const int vrow = lane >> 2;                       // 0..15
  const int vslot = (lane & 3) ^ ((vrow >> 1) & 3); // V: slot ^= (row>>1)&3
  const int sbase = sh * 1024;
  const unsigned short* kg = Kbh + (size_t)(sbase + krow) * 512 + kslot * 8;
  const unsigned short* vg = Vbh + (size_t)vrow * 2048 + sbase + vslot * 8;

  // read addressing
  const int ksw = ln31 & 7;
  const int vsw = (ln31 >> 1) & 3;
  const int krd = ln31 * 128;

  const short8 ones = {0x3F80, 0x3F80, 0x3F80, 0x3F80, 0x3F80, 0x3F80, 0x3F80, 0x3F80};
  f32x16 oA0 = {}, oA1 = {}, oB0 = {}, oB1 = {}, lA = {}, lB = {};

#define STAGE(t, bufi)                                                         \
  {                                                                            \
    const unsigned short* kp_ = kg + (size_t)(t) * 32 * 512;                   \
    const unsigned short* vp_ = vg + (t) * 32;                                 \
    char* kd_ = kbuf + (bufi) * 4096;                                          \
    char* vd_ = vbuf + (bufi) * 4096;                                          \
    GLOAD_LDS(kp_, kd_);                                                       \
    GLOAD_LDS(kp_ + (size_t)8 * 512, kd_ + 1024);                              \
    GLOAD_LDS(kp_ + (size_t)16 * 512, kd_ + 2048);                             \
    GLOAD_LDS(kp_ + (size_t)24 * 512, kd_ + 3072);                             \
    GLOAD_LDS(vp_, vd_);                                                       \
    GLOAD_LDS(vp_ + (size_t)16 * 2048, vd_ + 1024);                            \
    GLOAD_LDS(vp_ + (size_t)32 * 2048, vd_ + 2048);                            \
    GLOAD_LDS(vp_ + (size_t)48 * 2048, vd_ + 3072);                            \
  }

#define COMPUTE(bufi)                                                          \
  {                                                                            \
    const char* kr_ = kbuf + (bufi) * 4096;                                    \
    const char* vr_ = vbuf + (bufi) * 4096;                                    \
    short8 k0 = *(const short8*)(kr_ + krd + (((0 + hl) ^ ksw) << 4));         \
    short8 k1 = *(const short8*)(kr_ + krd + (((2 + hl) ^ ksw) << 4));         \
    short8 k2 = *(const short8*)(kr_ + krd + (((4 + hl) ^ ksw) << 4));         \
    short8 k3 = *(const short8*)(kr_ + krd + (((6 + hl) ^ ksw) << 4));         \
    short8 v00 = *(const short8*)(vr_ + (0 * 32 + ln31) * 64 + (((0 + hl) ^ vsw) << 4)); \
    short8 v01 = *(const short8*)(vr_ + (1 * 32 + ln31) * 64 + (((0 + hl) ^ vsw) << 4)); \
    short8 v10 = *(const short8*)(vr_ + (0 * 32 + ln31) * 64 + (((2 + hl) ^ vsw) << 4)); \
    short8 v11 = *(const short8*)(vr_ + (1 * 32 + ln31) * 64 + (((2 + hl) ^ vsw) << 4)); \
    f32x16 sA = {}, sB = {};                                                   \
    __builtin_amdgcn_s_setprio(1);                                             \
    sA = mfma32(k0, qfA[0], sA); sA = mfma32(k1, qfA[1], sA);                  \
    sA = mfma32(k2, qfA[2], sA); sA = mfma32(k3, qfA[3], sA);                  \
    sB = mfma32(k0, qfB[0], sB); sB = mfma32(k1, qfB[1], sB);                  \
    sB = mfma32(k2, qfB[2], sB); sB = mfma32(k3, qfB[3], sB);                  \
    __builtin_amdgcn_s_setprio(0);                                             \
    unsigned cA[8], cB[8];                                                     \
    _Pragma("unroll")                                                          \
    for (int i = 0; i < 8; ++i)                                                \
      cA[i] = cvtpk(__builtin_exp2f(sA[2 * i]), __builtin_exp2f(sA[2 * i + 1]));\
    _Pragma("unroll")                                                          \
    for (int i = 0; i < 8; ++i)                                                \
      cB[i] = cvtpk(__builtin_exp2f(sB[2 * i]), __builtin_exp2f(sB[2 * i + 1]));\
    {                                                                          \
      u32x2 r;                                                                 \
      r = __builtin_amdgcn_permlane32_swap(cA[0], cA[2], false, false); cA[0] = r[0]; cA[2] = r[1]; \
      r = __builtin_amdgcn_permlane32_swap(cA[1], cA[3], false, false); cA[1] = r[0]; cA[3] = r[1]; \
      r = __builtin_amdgcn_permlane32_swap(cA[4], cA[6], false, false); cA[4] = r[0]; cA[6] = r[1]; \
      r = __builtin_amdgcn_permlane32_swap(cA[5], cA[7], false, false); cA[5] = r[0]; cA[7] = r[1]; \
      r = __builtin_amdgcn_permlane32_swap(cB[0], cB[2], false, false); cB[0] = r[0]; cB[2] = r[1]; \
      r = __builtin_amdgcn_permlane32_swap(cB[1], cB[3], false, false); cB[1] = r[0]; cB[3] = r[1]; \
      r = __builtin_amdgcn_permlane32_swap(cB[4], cB[6], false, false); cB[4] = r[0]; cB[6] = r[1]; \
      r = __builtin_amdgcn_permlane32_swap(cB[5], cB[7], false, false); cB[5] = r[0]; cB[7] = r[1]; \
    }                                                                          \
    short8 pA0, pA1, pB0, pB1;                                                 \
    {                                                                          \
      union { unsigned u[4]; short8 s8; } t2;                                  \
      t2.u[0] = cA[0]; t2.u[1] = cA[1]; t2.u[2] = cA[2]; t2.u[3] = cA[3]; pA0 = t2.s8; \
      t2.u[0] = cA[4]; t2.u[1] = cA[5]; t2.u[2] = cA[6]; t2.u[3] = cA[7]; pA1 = t2.s8; \
      t2.u[0] = cB[0]; t2.u[1] = cB[1]; t2.u[2] = cB[2]; t2.u[3] = cB[3]; pB0 = t2.s8; \
      t2.u[0] = cB[4]; t2.u[1] = cB[5]; t2.u[2] = cB[6]; t2.u[3] = cB[7]; pB1 = t2.s8; \
    }                                                                          \
    __builtin_amdgcn_s_setprio(1);                                             \
    oA0 = mfma32(v00, pA0, oA0); oA1 = mfma32(v01, pA0, oA1);                  \
    oB0 = mfma32(v00, pB0, oB0); oB1 = mfma32(v01, pB0, oB1);                  \
    lA = mfma32(ones, pA0, lA);  lB = mfma32(ones, pB0, lB);                   \
    oA0 = mfma32(v10, pA1, oA0); oA1 = mfma32(v11, pA1, oA1);                  \
    oB0 = mfma32(v10, pB1, oB0); oB1 = mfma32(v11, pB1, oB1);                  \
    lA = mfma32(ones, pA1, lA);  lB = mfma32(ones, pB1, lB);                   \
    __builtin_amdgcn_s_setprio(0);                                             \
  }

  // clean vmcnt baseline (Q-frag loads drained), then prime 2 tiles
  asm volatile("s_waitcnt vmcnt(0)" ::: "memory");
  STAGE(0, 0);
  STAGE(1, 1);

#pragma unroll 1
  for (int t = 0; t < 31; ++t) {
    asm volatile("s_waitcnt vmcnt(8)" ::: "memory");  // tile t landed; t+1 in flight
    COMPUTE(t & 1);
    asm volatile("s_waitcnt lgkmcnt(0)" ::: "memory"); // reads of buf retired
    if (t < 30) STAGE(t + 2, t & 1);
  }
  asm volatile("s_waitcnt vmcnt(0)" ::: "memory");
  COMPUTE(1);

#undef STAGE
#undef COMPUTE

  // ---- combine s-halves (one barrier; unnormalized => plain adds) ----
  __syncthreads();
  float* reg = (float*)(LDS) + qh * 8192 + lane * 72;  // 288 B/lane record
  if (sh == 1) {
    float4* w4 = (float4*)reg;
#pragma unroll
    for (int i = 0; i < 4; ++i) {
      w4[i]      = make_float4(oA0[4*i], oA0[4*i+1], oA0[4*i+2], oA0[4*i+3]);
      w4[4 + i]  = make_float4(oA1[4*i], oA1[4*i+1], oA1[4*i+2], oA1[4*i+3]);
      w4[8 + i]  = make_float4(oB0[4*i], oB0[4*i+1], oB0[4*i+2], oB0[4*i+3]);
      w4[12 + i] = make_float4(oB1[4*i], oB1[4*i+1], oB1[4*i+2], oB1[4*i+3]);
    }
    reg[64] = lA[0]; reg[65] = lB[0];
  }
  __syncthreads();
  if (sh == 0) {
#pragma unroll
    for (int i = 0; i < 16; ++i) {
      oA0[i] += reg[i];      oA1[i] += reg[16 + i];
      oB0[i] += reg[32 + i]; oB1[i] += reg[48 + i];
    }
    float invA = 1.f / (lA[0] + reg[64]);
    float invB = 1.f / (lB[0] + reg[65]);
#pragma unroll
    for (int dblk = 0; dblk < 2; ++dblk) {
      const f32x16& a = dblk ? oA1 : oA0;
      const f32x16& bb = dblk ? oB1 : oB0;
#pragma unroll
      for (int rg = 0; rg < 4; ++rg) {
        int d0 = dblk * 32 + rg * 8 + hl * 4;
        uint2 w;
        w.x = cvtpk(a[rg * 4 + 0] * invA, a[rg * 4 + 1] * invA);
        w.y = cvtpk(a[rg * 4 + 2] * invA, a[rg * 4 + 3] * invA);
        *(uint2*)(Og + ((size_t)b * 2048 + q0) * 512 + h * 64 + d0) = w;
        w.x = cvtpk(bb[rg * 4 + 0] * invB, bb[rg * 4 + 1] * invB);
        w.y = cvtpk(bb[rg * 4 + 2] * invB, bb[rg * 4 + 3] * invB);
        *(uint2*)(Og + ((size_t)b * 2048 + q0 + 32) * 512 + h * 64 + d0) = w;
      }
    }
  }
}

// ---------------------------------------------------------------------------
extern "C" void kernel_launch(void* const* d_in, const int* in_sizes, int n_in,
                              void* d_out, int out_size, void* d_ws, size_t ws_size,
                              hipStream_t stream) {
  (void)in_sizes; (void)n_in; (void)out_size; (void)ws_size;
  const float* query = (const float*)d_in[0];
  const float* key   = (const float*)d_in[1];
  const float* value = (const float*)d_in[2];
  const float* Wq    = (const float*)d_in[3];
  const float* Wk    = (const float*)d_in[4];
  const float* Wv    = (const float*)d_in[5];
  const float* Wo    = (const float*)d_in[6];

  const size_t TOK = (size_t)NB * NL * MODEL;
  unsigned short* Qw = (unsigned short*)d_ws;
  unsigned short* Kw = Qw + TOK;
  unsigned short* Vw = Kw + TOK;   // transposed [b][h*64+d][s]
  unsigned short* Aw = Vw + TOK;   // attended [b][l][512]

  qkv512<<<768, 256, 0, stream>>>(query, key, value, Wq, Wk, Wv, Qw, Kw, Vw);
  attn_nb<<<512, 256, 0, stream>>>(Qw, Kw, Vw, Aw);
  gemmWo<<<256, 256, 0, stream>>>(Aw, Wo, (float*)d_out);
}